// Round 3
// baseline (228.580 us; speedup 1.0000x reference)
//
#include <hip/hip_runtime.h>
#include <hip/hip_bf16.h>

#define B_SZ 8
#define SEQ 1024
#define DIM_ 1024
#define NH 16
#define HD 64
#define M_TOT (B_SZ*SEQ)   // 8192
#define N_QKV (3*DIM_)     // 3072

typedef __attribute__((ext_vector_type(8))) short bf16x8;
typedef __attribute__((ext_vector_type(4))) float f32x4;

typedef const __attribute__((address_space(1))) void gvoid;
typedef __attribute__((address_space(3))) void lvoid;

__device__ __forceinline__ short f2bf(float f){
  union { __hip_bfloat16 h; short s; } u;
  u.h = __float2bfloat16(f);
  return u.s;
}

// ---------------- kernel 1: fp32 -> bf16 elementwise ----------------
__global__ void cvt_kernel(const float* __restrict__ in, short* __restrict__ out, int n4){
  int i = blockIdx.x*blockDim.x + threadIdx.x;
  int stride = gridDim.x*blockDim.x;
  for (; i < n4; i += stride){
    float4 v = reinterpret_cast<const float4*>(in)[i];
    short4 s;
    s.x = f2bf(v.x); s.y = f2bf(v.y); s.z = f2bf(v.z); s.w = f2bf(v.w);
    reinterpret_cast<short4*>(out)[i] = s;
  }
}

// ------- kernel 2: transpose+convert fp32 [R][C] -> bf16 [C][R] -------
__global__ void tconv_kernel(const float* __restrict__ in, short* __restrict__ out, int R, int C){
  __shared__ alignas(16) short tile[64][66];
  const int l = threadIdx.x & 63, w = threadIdx.x >> 6;
  const int r0 = blockIdx.y * 64, c0 = blockIdx.x * 64;
  #pragma unroll
  for (int rr = 0; rr < 16; ++rr){
    int r = w + rr*4;
    tile[r][l] = f2bf(in[(size_t)(r0+r)*C + c0 + l]);
  }
  __syncthreads();
  #pragma unroll
  for (int cc = 0; cc < 16; ++cc){
    int c = w + cc*4;
    out[(size_t)(c0+c)*R + r0 + l] = tile[l][c];
  }
}

// ---------- kernel 3: bf16 GEMM 128x256, BK=64, 8 waves, dbuf ----------
// C = A[M][K] * Bt[N][K]^T.  T2 swizzle (word ^= row&7), T3-min pipeline.
// EPI=0: scatter q/k/vT.  EPI=1: +bias, fp32 out.
template<int EPI>
__global__ __launch_bounds__(512, 2) void gemm2(
    const short* __restrict__ A, const short* __restrict__ Bt,
    int M, int Nn, int K,
    short* __restrict__ Qb, short* __restrict__ Kb, short* __restrict__ Vtb,
    const float* __restrict__ bias, float* __restrict__ outF)
{
  __shared__ alignas(16) short As[2][128*64];   // 2 x 16 KiB
  __shared__ alignas(16) short Bs[2][256*64];   // 2 x 32 KiB  (96 KiB total)

  const int tid = threadIdx.x;           // 0..511
  const int l = tid & 63, wid = tid >> 6;
  const int wr = wid >> 2, wc = wid & 3; // 2M x 4N waves
  const int lr = l & 15, lw = l >> 4;    // fragment row lane, k-word lane
  const int sw = lr & 7;                 // swizzle key (row & 7 == lr & 7)
  const int m0 = blockIdx.y * 128, n0 = blockIdx.x * 256;

  f32x4 acc[4][4];
  const f32x4 zz = {0.f,0.f,0.f,0.f};
  #pragma unroll
  for (int m=0;m<4;m++)
    #pragma unroll
    for (int n=0;n<4;n++) acc[m][n] = zz;

  // staging: linear LDS dest, inverse-swizzled global source (G21 / T2)
  const int srow_a0 = tid >> 3;                 // A rows for j=0 (j=1: +64)
  const int sword   = tid & 7;
  auto STAGE = [&](int buf, int kt){
    const int k0 = kt*64;
    #pragma unroll
    for (int j=0;j<2;j++){
      const int idx = j*512 + tid;
      const int row = srow_a0 + j*64;
      const int ws  = sword ^ (row & 7);
      __builtin_amdgcn_global_load_lds(
          (gvoid*)(A + (size_t)(m0+row)*K + k0 + ws*8),
          (lvoid*)(&As[buf][idx*8]), 16, 0, 0);
    }
    #pragma unroll
    for (int j=0;j<4;j++){
      const int idx = j*512 + tid;
      const int row = srow_a0 + j*64;
      const int ws  = sword ^ (row & 7);
      __builtin_amdgcn_global_load_lds(
          (gvoid*)(Bt + (size_t)(n0+row)*K + k0 + ws*8),
          (lvoid*)(&Bs[buf][idx*8]), 16, 0, 0);
    }
  };

  STAGE(0, 0);
  __syncthreads();          // drains vmcnt(0) before first reads

  const int NT = K >> 6;    // 16 K-tiles
  int buf = 0;
  for (int kt = 0; kt < NT; ++kt){
    if (kt + 1 < NT) STAGE(buf ^ 1, kt + 1);   // issue loads FIRST (T3)

    // fragment reads (swizzled): A 8 x b128, B 8 x b128
    bf16x8 af[4][2], bfr[4][2];
    #pragma unroll
    for (int m=0;m<4;m++){
      const int r = wr*64 + m*16 + lr;
      #pragma unroll
      for (int ks=0;ks<2;ks++){
        const int w = (lw + 4*ks) ^ sw;
        af[m][ks] = *(const bf16x8*)(&As[buf][r*64 + w*8]);
      }
    }
    #pragma unroll
    for (int n=0;n<4;n++){
      const int r = wc*64 + n*16 + lr;
      #pragma unroll
      for (int ks=0;ks<2;ks++){
        const int w = (lw + 4*ks) ^ sw;
        bfr[n][ks] = *(const bf16x8*)(&Bs[buf][r*64 + w*8]);
      }
    }

    __builtin_amdgcn_s_setprio(1);
    #pragma unroll
    for (int ks=0;ks<2;ks++)
      #pragma unroll
      for (int m=0;m<4;m++)
        #pragma unroll
        for (int n=0;n<4;n++)
          acc[m][n] = __builtin_amdgcn_mfma_f32_16x16x32_bf16(af[m][ks], bfr[n][ks], acc[m][n], 0, 0, 0);
    __builtin_amdgcn_s_setprio(0);

    __syncthreads();        // one vmcnt(0)+lgkmcnt(0)+barrier per K-tile
    buf ^= 1;
  }

  // epilogue
  #pragma unroll
  for (int n=0;n<4;n++){
    const int col = n0 + wc*64 + n*16 + lr;
    float bv = 0.f;
    if (EPI == 1) bv = bias[col];
    #pragma unroll
    for (int m=0;m<4;m++){
      const int rbase = m0 + wr*64 + m*16 + (lw<<2);
      #pragma unroll
      for (int ri=0;ri<4;ri++){
        const int row = rbase + ri;
        const float v = acc[m][n][ri];
        if (EPI == 0){
          const int three = col >> 10;
          const int cc = col & 1023;
          const int h = cc >> 6, d = cc & 63;
          const int b = row >> 10, nn = row & 1023;
          const int bh = b*NH + h;
          // Q pre-scaled by HD^-0.5 * log2(e) -> softmax in exp2 domain
          if (three == 0)      Qb[((size_t)bh*SEQ + nn)*HD + d] = f2bf(v * 0.1803368801f);
          else if (three == 1) Kb[((size_t)bh*SEQ + nn)*HD + d] = f2bf(v);
          else                 Vtb[((size_t)bh*HD + d)*SEQ + nn] = f2bf(v);
        } else {
          outF[(size_t)row*Nn + col] = v + bv;
        }
      }
    }
  }
}

// ---------------- kernel 4: flash attention (swapped QK^T) ----------------
// grid: B*H*(SEQ/64). block: 256 (4 waves x 16 q-rows). KVBLK=64, dbuf.
__global__ __launch_bounds__(256) void attn_kernel(
    const short* __restrict__ Q, const short* __restrict__ Kb,
    const short* __restrict__ Vt, short* __restrict__ Ao)
{
  __shared__ alignas(16) short Ks[2][64*72];
  __shared__ alignas(16) short Vs[2][64*72];
  __shared__ alignas(16) short Ps[4][16*72];

  const int tid = threadIdx.x;
  const int l = tid & 63, w = tid >> 6;
  const int bid = blockIdx.x;
  const int qt = bid & 15, bh = bid >> 4;
  const int b = bh >> 4, h = bh & 15;
  const size_t base = (size_t)bh << 16;   // bh * SEQ * HD

  const int lr = l & 15;
  const int q4 = l >> 4;
  const int lk = q4 << 3;

  // Q fragments (pre-scaled by HD^-0.5*log2e in QKV epilogue)
  const int qrow = qt*64 + w*16 + lr;
  const short* qp = Q + base + (size_t)qrow*HD + lk;
  const bf16x8 qf0 = *(const bf16x8*)qp;
  const bf16x8 qf1 = *(const bf16x8*)(qp + 32);

  float m_run = -1e30f, l_run = 0.f;
  f32x4 o[4];
  #pragma unroll
  for (int i=0;i<4;i++) o[i] = f32x4{0.f,0.f,0.f,0.f};

  bf16x8 kr[2], vr[2];
  auto load_tile = [&](int kt){
    const int kv0 = kt*64;
    #pragma unroll
    for (int p=0;p<2;p++){
      const int idx = tid + p*256;
      const int row = idx >> 3, c8 = (idx & 7) << 3;
      kr[p] = *(const bf16x8*)(Kb + base + (size_t)(kv0+row)*HD + c8);
      vr[p] = *(const bf16x8*)(Vt + base + (size_t)row*SEQ + kv0 + c8);
    }
  };
  auto write_tile = [&](int bi){
    #pragma unroll
    for (int p=0;p<2;p++){
      const int idx = tid + p*256;
      const int row = idx >> 3, c8 = (idx & 7) << 3;
      *(bf16x8*)(&Ks[bi][row*72 + c8]) = kr[p];
      *(bf16x8*)(&Vs[bi][row*72 + c8]) = vr[p];
    }
  };

  load_tile(0);
  write_tile(0);
  __syncthreads();

  int cur = 0;
  for (int kt = 0; kt < 16; ++kt){
    if (kt < 15) load_tile(kt+1);   // HBM loads overlap compute

    const short* kb = &Ks[cur][0];
    const short* vb = &Vs[cur][0];

    // S^T = K Q^T: lane holds S[k' = cg*16 + q4*4 + ri][q = lane&15]
    f32x4 s[4];
    #pragma unroll
    for (int cg=0;cg<4;cg++) s[cg] = f32x4{0.f,0.f,0.f,0.f};
    __builtin_amdgcn_s_setprio(1);
    #pragma unroll
    for (int cg=0;cg<4;cg++){
      const short* kp = kb + (cg*16 + lr)*72 + lk;
      bf16x8 kf0 = *(const bf16x8*)kp;
      bf16x8 kf1 = *(const bf16x8*)(kp + 32);
      s[cg] = __builtin_amdgcn_mfma_f32_16x16x32_bf16(kf0, qf0, s[cg], 0,0,0);
      s[cg] = __builtin_amdgcn_mfma_f32_16x16x32_bf16(kf1, qf1, s[cg], 0,0,0);
    }
    __builtin_amdgcn_s_setprio(0);

    // online softmax for this lane's q-row (exp2 domain)
    float mt = s[0][0];
    #pragma unroll
    for (int cg=0;cg<4;cg++)
      #pragma unroll
      for (int ri=0;ri<4;ri++) mt = fmaxf(mt, s[cg][ri]);
    mt = fmaxf(mt, __shfl_xor(mt, 16));
    mt = fmaxf(mt, __shfl_xor(mt, 32));

    const float mn = fmaxf(m_run, mt);
    const float corr = __builtin_amdgcn_exp2f(m_run - mn);
    m_run = mn;

    float p[4][4], rs = 0.f;
    #pragma unroll
    for (int cg=0;cg<4;cg++)
      #pragma unroll
      for (int ri=0;ri<4;ri++){
        p[cg][ri] = __builtin_amdgcn_exp2f(s[cg][ri] - mn);
        rs += p[cg][ri];
      }
    rs += __shfl_xor(rs, 16);
    rs += __shfl_xor(rs, 32);
    l_run = l_run*corr + rs;

    // P -> LDS as [q][k'] (wave-local buffer; lgkmcnt orders write->read)
    short* pw = &Ps[w][0];
    #pragma unroll
    for (int cg=0;cg<4;cg++){
      short4 pk;
      pk.x = f2bf(p[cg][0]); pk.y = f2bf(p[cg][1]);
      pk.z = f2bf(p[cg][2]); pk.w = f2bf(p[cg][3]);
      *(short4*)(pw + lr*72 + cg*16 + q4*4) = pk;
    }

    // redistribute corr (per q=lane&15) to O rows (q = q4*4+ri)
    float corr_r[4];
    #pragma unroll
    for (int ri=0;ri<4;ri++) corr_r[ri] = __shfl(corr, (q4<<2) + ri);
    #pragma unroll
    for (int dg=0;dg<4;dg++)
      #pragma unroll
      for (int ri=0;ri<4;ri++) o[dg][ri] *= corr_r[ri];

    const bf16x8 pa0 = *(const bf16x8*)(pw + lr*72 + lk);
    const bf16x8 pa1 = *(const bf16x8*)(pw + lr*72 + lk + 32);
    __builtin_amdgcn_s_setprio(1);
    #pragma unroll
    for (int dg=0;dg<4;dg++){
      const short* vp = vb + (dg*16 + lr)*72 + lk;
      bf16x8 vf0 = *(const bf16x8*)vp;
      bf16x8 vf1 = *(const bf16x8*)(vp + 32);
      o[dg] = __builtin_amdgcn_mfma_f32_16x16x32_bf16(pa0, vf0, o[dg], 0,0,0);
      o[dg] = __builtin_amdgcn_mfma_f32_16x16x32_bf16(pa1, vf1, o[dg], 0,0,0);
    }
    __builtin_amdgcn_s_setprio(0);

    if (kt < 15) write_tile(cur ^ 1);
    __syncthreads();
    cur ^= 1;
  }

  // epilogue: O /= l, write bf16 [B*SEQ][DIM]
  float linv[4];
  #pragma unroll
  for (int ri=0;ri<4;ri++) linv[ri] = 1.0f / __shfl(l_run, (q4<<2) + ri);
  #pragma unroll
  for (int ri=0;ri<4;ri++){
    const int row = qt*64 + w*16 + (q4<<2) + ri;
    short* op = Ao + ((size_t)(b*SEQ + row))*DIM_ + h*HD;
    #pragma unroll
    for (int dg=0;dg<4;dg++)
      op[dg*16 + lr] = f2bf(o[dg][ri] * linv[ri]);
  }
}

// ---------------------------- launcher ----------------------------
extern "C" void kernel_launch(void* const* d_in, const int* in_sizes, int n_in,
                              void* d_out, int out_size, void* d_ws, size_t ws_size,
                              hipStream_t stream)
{
  (void)in_sizes; (void)n_in; (void)out_size; (void)ws_size;
  const float* x     = (const float*)d_in[0];
  const float* w_qkv = (const float*)d_in[1];
  const float* w_out = (const float*)d_in[2];
  const float* b_out = (const float*)d_in[3];
  float* out = (float*)d_out;

  char* ws = (char*)d_ws;
  const size_t MB = (size_t)1 << 20;
  short* xb    = (short*)(ws);            // 16 MiB  x bf16 [8192][1024]
  short* wqkvT = (short*)(ws + 16*MB);    //  6 MiB  w_qkv^T bf16 [3072][1024]
  short* woutT = (short*)(ws + 22*MB);    //  2 MiB  w_out^T bf16 [1024][1024]
  short* Qb    = (short*)(ws + 24*MB);    // 16 MiB  [bh][n][64] (pre-scaled)
  short* Kb    = (short*)(ws + 40*MB);    // 16 MiB  [bh][n][64]
  short* Vtb   = (short*)(ws + 56*MB);    // 16 MiB  [bh][64][n]
  short* Aob   = (short*)(ws + 72*MB);    // 16 MiB  attn out bf16 [8192][1024]

  cvt_kernel<<<2048, 256, 0, stream>>>(x, xb, (M_TOT*DIM_)/4);
  tconv_kernel<<<dim3(N_QKV/64, DIM_/64), 256, 0, stream>>>(w_qkv, wqkvT, DIM_, N_QKV);
  tconv_kernel<<<dim3(DIM_/64, DIM_/64), 256, 0, stream>>>(w_out, woutT, DIM_, DIM_);

  gemm2<0><<<dim3(N_QKV/256, M_TOT/128), 512, 0, stream>>>(
      xb, wqkvT, M_TOT, N_QKV, DIM_, Qb, Kb, Vtb, nullptr, nullptr);

  attn_kernel<<<B_SZ*NH*(SEQ/64), 256, 0, stream>>>(Qb, Kb, Vtb, Aob);

  gemm2<1><<<dim3(DIM_/256, M_TOT/128), 512, 0, stream>>>(
      Aob, woutT, M_TOT, DIM_, DIM_, nullptr, nullptr, nullptr, b_out, out);
}

// Round 4
// 218.119 us; speedup vs baseline: 1.0480x; 1.0480x over previous
//
#include <hip/hip_runtime.h>
#include <hip/hip_bf16.h>

#define B_SZ 8
#define SEQ 1024
#define DIM_ 1024
#define NH 16
#define HD 64
#define M_TOT (B_SZ*SEQ)   // 8192
#define N_QKV (3*DIM_)     // 3072

typedef __attribute__((ext_vector_type(8))) short bf16x8;
typedef __attribute__((ext_vector_type(4))) float f32x4;

typedef const __attribute__((address_space(1))) void gvoid;
typedef __attribute__((address_space(3))) void lvoid;

__device__ __forceinline__ short f2bf(float f){
  union { __hip_bfloat16 h; short s; } u;
  u.h = __float2bfloat16(f);
  return u.s;
}

// ---------------- kernel 1: fp32 -> bf16 elementwise ----------------
__global__ void cvt_kernel(const float* __restrict__ in, short* __restrict__ out, int n4){
  int i = blockIdx.x*blockDim.x + threadIdx.x;
  int stride = gridDim.x*blockDim.x;
  for (; i < n4; i += stride){
    float4 v = reinterpret_cast<const float4*>(in)[i];
    short4 s;
    s.x = f2bf(v.x); s.y = f2bf(v.y); s.z = f2bf(v.z); s.w = f2bf(v.w);
    reinterpret_cast<short4*>(out)[i] = s;
  }
}

// ------- kernel 2: transpose+convert fp32 [R][C] -> bf16 [C][R] -------
__global__ void tconv_kernel(const float* __restrict__ in, short* __restrict__ out, int R, int C){
  __shared__ alignas(16) short tile[64][66];
  const int l = threadIdx.x & 63, w = threadIdx.x >> 6;
  const int r0 = blockIdx.y * 64, c0 = blockIdx.x * 64;
  #pragma unroll
  for (int rr = 0; rr < 16; ++rr){
    int r = w + rr*4;
    tile[r][l] = f2bf(in[(size_t)(r0+r)*C + c0 + l]);
  }
  __syncthreads();
  #pragma unroll
  for (int cc = 0; cc < 16; ++cc){
    int c = w + cc*4;
    out[(size_t)(c0+c)*R + r0 + l] = tile[l][c];
  }
}

// ---- kernel 3: bf16 GEMM, phase-scheduled (raw s_barrier, counted drain) ----
// C = A[M][K] * Bt[N][K]^T.  8 waves (2M x 4N).  BK=64, dbuf LDS.
// T2 swizzle (word ^= row&7, pre-swizzled global source).  T5 setprio.
// EPI=0: scatter q/k/vT.  EPI=1: +bias, fp32 out.
template<int BM, int BN, int EPI>
__global__ __launch_bounds__(512, 2) void gemm3(
    const short* __restrict__ A, const short* __restrict__ Bt,
    int M, int Nn, int K,
    short* __restrict__ Qb, short* __restrict__ Kb, short* __restrict__ Vtb,
    const float* __restrict__ bias, float* __restrict__ outF)
{
  constexpr int MF  = BM/32;                 // M frags per wave (8 or 4)
  constexpr int NF  = BN/64;                 // N frags per wave (3 or 4)
  constexpr int NPH = (MF==8) ? 4 : 2;       // phases per K-tile
  constexpr int MH2 = MF/(NPH/2);            // M frags per phase (4)
  constexpr int AJ  = BM/64;                 // A stage-loads per thread
  constexpr int BJ  = BN/64;                 // B stage-loads per thread

  __shared__ alignas(16) short As[2][BM*64];
  __shared__ alignas(16) short Bs[2][BN*64];

  const int tid = threadIdx.x;               // 0..511
  const int l = tid & 63, wid = tid >> 6;
  const int wrM = wid >> 2, wc = wid & 3;    // 2M x 4N waves
  const int lr = l & 15, lw = l >> 4;
  const int sw = lr & 7;                     // swizzle key (row&7 == lr&7)
  const int m0 = blockIdx.y * BM, n0 = blockIdx.x * BN;

  f32x4 acc[MF][NF];
  const f32x4 zz = {0.f,0.f,0.f,0.f};
  #pragma unroll
  for (int m=0;m<MF;m++)
    #pragma unroll
    for (int n=0;n<NF;n++) acc[m][n] = zz;

  // staging: linear LDS dest, inverse-swizzled global source (G21 / T2)
  auto stageA = [&](int buf, int k0, int j){
    const int idx = j*512 + tid;
    const int row = idx >> 3;
    const int ws  = (idx & 7) ^ (row & 7);
    __builtin_amdgcn_global_load_lds(
        (gvoid*)(A + (size_t)(m0+row)*K + k0 + ws*8),
        (lvoid*)(&As[buf][idx*8]), 16, 0, 0);
  };
  auto stageB = [&](int buf, int k0, int j){
    const int idx = j*512 + tid;
    const int row = idx >> 3;
    const int ws  = (idx & 7) ^ (row & 7);
    __builtin_amdgcn_global_load_lds(
        (gvoid*)(Bt + (size_t)(n0+row)*K + k0 + ws*8),
        (lvoid*)(&Bs[buf][idx*8]), 16, 0, 0);
  };

  // prologue: stage tile 0, drain, barrier
  #pragma unroll
  for (int j=0;j<AJ;j++) stageA(0, 0, j);
  #pragma unroll
  for (int j=0;j<BJ;j++) stageB(0, 0, j);
  asm volatile("s_waitcnt vmcnt(0)" ::: "memory");
  __builtin_amdgcn_s_barrier();

  const int NT = K >> 6;
  int buf = 0;
  bf16x8 bfr[NF];
  for (int kt = 0; kt < NT; ++kt){
    const bool pf = (kt + 1 < NT);
    const int k1 = (kt + 1) << 6;
    #pragma unroll
    for (int p = 0; p < NPH; ++p){
      const int ks = (NPH==4) ? (p>>1) : p;
      const int mh = (NPH==4) ? (p&1)  : 0;
      const int wsel = (lw + 4*ks) ^ sw;

      // ds-read this phase's operand subtile (swizzled)
      bf16x8 af[MH2];
      #pragma unroll
      for (int i=0;i<MH2;i++){
        const int r = wrM*(BM/2) + (mh*MH2+i)*16 + lr;
        af[i] = *(const bf16x8*)(&As[buf][r*64 + wsel*8]);
      }
      if (mh == 0){
        #pragma unroll
        for (int n=0;n<NF;n++){
          const int r = wc*(BN/4) + n*16 + lr;
          bfr[n] = *(const bf16x8*)(&Bs[buf][r*64 + wsel*8]);
        }
      }

      // stage next tile early (phases 0-1) so boundary drain is covered
      if (pf){
        if (NPH == 4){
          if (p == 0){ stageA(buf^1,k1,0); stageA(buf^1,k1,1); stageB(buf^1,k1,0); }
          else if (p == 1){ stageA(buf^1,k1,2); stageA(buf^1,k1,3); stageB(buf^1,k1,1); }
          else if (p == 2){ stageB(buf^1,k1,2); if (BJ > 3) stageB(buf^1,k1,3); }
        } else {
          if (p == 0){
            #pragma unroll
            for (int j=0;j<AJ;j++) stageA(buf^1,k1,j);
            #pragma unroll
            for (int j=0;j<BJ;j++) stageB(buf^1,k1,j);
          }
        }
      }

      __builtin_amdgcn_s_barrier();
      asm volatile("s_waitcnt lgkmcnt(0)" ::: "memory");
      __builtin_amdgcn_sched_barrier(0);
      __builtin_amdgcn_s_setprio(1);
      #pragma unroll
      for (int i=0;i<MH2;i++)
        #pragma unroll
        for (int n=0;n<NF;n++)
          acc[mh*MH2+i][n] = __builtin_amdgcn_mfma_f32_16x16x32_bf16(af[i], bfr[n], acc[mh*MH2+i][n], 0, 0, 0);
      __builtin_amdgcn_s_setprio(0);
      if (p == NPH-1)
        asm volatile("s_waitcnt vmcnt(0)" ::: "memory");   // next tile landed
      __builtin_amdgcn_s_barrier();
    }
    buf ^= 1;
  }

  // epilogue
  #pragma unroll
  for (int n=0;n<NF;n++){
    const int col = n0 + wc*(BN/4) + n*16 + lr;
    float bv = 0.f;
    if (EPI == 1) bv = bias[col];
    #pragma unroll
    for (int m=0;m<MF;m++){
      const int rbase = m0 + wrM*(BM/2) + m*16 + (lw<<2);
      #pragma unroll
      for (int ri=0;ri<4;ri++){
        const int row = rbase + ri;
        const float v = acc[m][n][ri];
        if (EPI == 0){
          const int three = col >> 10;
          const int cc = col & 1023;
          const int h = cc >> 6, d = cc & 63;
          const int b = row >> 10, nn = row & 1023;
          const int bh = b*NH + h;
          // Q pre-scaled by HD^-0.5 * log2(e) -> softmax in exp2 domain
          if (three == 0)      Qb[((size_t)bh*SEQ + nn)*HD + d] = f2bf(v * 0.1803368801f);
          else if (three == 1) Kb[((size_t)bh*SEQ + nn)*HD + d] = f2bf(v);
          else                 Vtb[((size_t)bh*HD + d)*SEQ + nn] = f2bf(v);
        } else {
          outF[(size_t)row*Nn + col] = v + bv;
        }
      }
    }
  }
}

// ---------------- kernel 4: flash attention (swapped QK^T) ----------------
// grid: B*H*(SEQ/64). block: 256 (4 waves x 16 q-rows). KVBLK=64, dbuf.
__global__ __launch_bounds__(256) void attn_kernel(
    const short* __restrict__ Q, const short* __restrict__ Kb,
    const short* __restrict__ Vt, short* __restrict__ Ao)
{
  __shared__ alignas(16) short Ks[2][64*72];
  __shared__ alignas(16) short Vs[2][64*72];
  __shared__ alignas(16) short Ps[4][16*72];

  const int tid = threadIdx.x;
  const int l = tid & 63, w = tid >> 6;
  const int bid = blockIdx.x;
  const int qt = bid & 15, bh = bid >> 4;
  const int b = bh >> 4, h = bh & 15;
  const size_t base = (size_t)bh << 16;   // bh * SEQ * HD

  const int lr = l & 15;
  const int q4 = l >> 4;
  const int lk = q4 << 3;

  // Q fragments (pre-scaled by HD^-0.5*log2e in QKV epilogue)
  const int qrow = qt*64 + w*16 + lr;
  const short* qp = Q + base + (size_t)qrow*HD + lk;
  const bf16x8 qf0 = *(const bf16x8*)qp;
  const bf16x8 qf1 = *(const bf16x8*)(qp + 32);

  float m_run = -1e30f, l_run = 0.f;
  f32x4 o[4];
  #pragma unroll
  for (int i=0;i<4;i++) o[i] = f32x4{0.f,0.f,0.f,0.f};

  bf16x8 kr[2], vr[2];
  auto load_tile = [&](int kt){
    const int kv0 = kt*64;
    #pragma unroll
    for (int p=0;p<2;p++){
      const int idx = tid + p*256;
      const int row = idx >> 3, c8 = (idx & 7) << 3;
      kr[p] = *(const bf16x8*)(Kb + base + (size_t)(kv0+row)*HD + c8);
      vr[p] = *(const bf16x8*)(Vt + base + (size_t)row*SEQ + kv0 + c8);
    }
  };
  auto write_tile = [&](int bi){
    #pragma unroll
    for (int p=0;p<2;p++){
      const int idx = tid + p*256;
      const int row = idx >> 3, c8 = (idx & 7) << 3;
      *(bf16x8*)(&Ks[bi][row*72 + c8]) = kr[p];
      *(bf16x8*)(&Vs[bi][row*72 + c8]) = vr[p];
    }
  };

  load_tile(0);
  write_tile(0);
  __syncthreads();

  int cur = 0;
  for (int kt = 0; kt < 16; ++kt){
    if (kt < 15) load_tile(kt+1);   // HBM loads overlap compute

    const short* kb = &Ks[cur][0];
    const short* vb = &Vs[cur][0];

    // S^T = K Q^T: lane holds S[k' = cg*16 + q4*4 + ri][q = lane&15]
    f32x4 s[4];
    #pragma unroll
    for (int cg=0;cg<4;cg++) s[cg] = f32x4{0.f,0.f,0.f,0.f};
    __builtin_amdgcn_s_setprio(1);
    #pragma unroll
    for (int cg=0;cg<4;cg++){
      const short* kp = kb + (cg*16 + lr)*72 + lk;
      bf16x8 kf0 = *(const bf16x8*)kp;
      bf16x8 kf1 = *(const bf16x8*)(kp + 32);
      s[cg] = __builtin_amdgcn_mfma_f32_16x16x32_bf16(kf0, qf0, s[cg], 0,0,0);
      s[cg] = __builtin_amdgcn_mfma_f32_16x16x32_bf16(kf1, qf1, s[cg], 0,0,0);
    }
    __builtin_amdgcn_s_setprio(0);

    // online softmax for this lane's q-row (exp2 domain)
    float mt = s[0][0];
    #pragma unroll
    for (int cg=0;cg<4;cg++)
      #pragma unroll
      for (int ri=0;ri<4;ri++) mt = fmaxf(mt, s[cg][ri]);
    mt = fmaxf(mt, __shfl_xor(mt, 16));
    mt = fmaxf(mt, __shfl_xor(mt, 32));

    const float mn = fmaxf(m_run, mt);
    const float corr = __builtin_amdgcn_exp2f(m_run - mn);
    m_run = mn;

    float p[4][4], rs = 0.f;
    #pragma unroll
    for (int cg=0;cg<4;cg++)
      #pragma unroll
      for (int ri=0;ri<4;ri++){
        p[cg][ri] = __builtin_amdgcn_exp2f(s[cg][ri] - mn);
        rs += p[cg][ri];
      }
    rs += __shfl_xor(rs, 16);
    rs += __shfl_xor(rs, 32);
    l_run = l_run*corr + rs;

    // P -> LDS as [q][k'] (wave-local buffer; lgkmcnt orders write->read)
    short* pw = &Ps[w][0];
    #pragma unroll
    for (int cg=0;cg<4;cg++){
      short4 pk;
      pk.x = f2bf(p[cg][0]); pk.y = f2bf(p[cg][1]);
      pk.z = f2bf(p[cg][2]); pk.w = f2bf(p[cg][3]);
      *(short4*)(pw + lr*72 + cg*16 + q4*4) = pk;
    }

    // redistribute corr (per q=lane&15) to O rows (q = q4*4+ri)
    float corr_r[4];
    #pragma unroll
    for (int ri=0;ri<4;ri++) corr_r[ri] = __shfl(corr, (q4<<2) + ri);
    #pragma unroll
    for (int dg=0;dg<4;dg++)
      #pragma unroll
      for (int ri=0;ri<4;ri++) o[dg][ri] *= corr_r[ri];

    const bf16x8 pa0 = *(const bf16x8*)(pw + lr*72 + lk);
    const bf16x8 pa1 = *(const bf16x8*)(pw + lr*72 + lk + 32);
    __builtin_amdgcn_s_setprio(1);
    #pragma unroll
    for (int dg=0;dg<4;dg++){
      const short* vp = vb + (dg*16 + lr)*72 + lk;
      bf16x8 vf0 = *(const bf16x8*)vp;
      bf16x8 vf1 = *(const bf16x8*)(vp + 32);
      o[dg] = __builtin_amdgcn_mfma_f32_16x16x32_bf16(pa0, vf0, o[dg], 0,0,0);
      o[dg] = __builtin_amdgcn_mfma_f32_16x16x32_bf16(pa1, vf1, o[dg], 0,0,0);
    }
    __builtin_amdgcn_s_setprio(0);

    if (kt < 15) write_tile(cur ^ 1);
    __syncthreads();
    cur ^= 1;
  }

  // epilogue: O /= l, write bf16 [B*SEQ][DIM]
  float linv[4];
  #pragma unroll
  for (int ri=0;ri<4;ri++) linv[ri] = 1.0f / __shfl(l_run, (q4<<2) + ri);
  #pragma unroll
  for (int ri=0;ri<4;ri++){
    const int row = qt*64 + w*16 + (q4<<2) + ri;
    short* op = Ao + ((size_t)(b*SEQ + row))*DIM_ + h*HD;
    #pragma unroll
    for (int dg=0;dg<4;dg++)
      op[dg*16 + lr] = f2bf(o[dg][ri] * linv[ri]);
  }
}

// ---------------------------- launcher ----------------------------
extern "C" void kernel_launch(void* const* d_in, const int* in_sizes, int n_in,
                              void* d_out, int out_size, void* d_ws, size_t ws_size,
                              hipStream_t stream)
{
  (void)in_sizes; (void)n_in; (void)out_size; (void)ws_size;
  const float* x     = (const float*)d_in[0];
  const float* w_qkv = (const float*)d_in[1];
  const float* w_out = (const float*)d_in[2];
  const float* b_out = (const float*)d_in[3];
  float* out = (float*)d_out;

  char* ws = (char*)d_ws;
  const size_t MB = (size_t)1 << 20;
  short* xb    = (short*)(ws);            // 16 MiB  x bf16 [8192][1024]
  short* wqkvT = (short*)(ws + 16*MB);    //  6 MiB  w_qkv^T bf16 [3072][1024]
  short* woutT = (short*)(ws + 22*MB);    //  2 MiB  w_out^T bf16 [1024][1024]
  short* Qb    = (short*)(ws + 24*MB);    // 16 MiB  [bh][n][64] (pre-scaled)
  short* Kb    = (short*)(ws + 40*MB);    // 16 MiB  [bh][n][64]
  short* Vtb   = (short*)(ws + 56*MB);    // 16 MiB  [bh][64][n]
  short* Aob   = (short*)(ws + 72*MB);    // 16 MiB  attn out bf16 [8192][1024]

  cvt_kernel<<<2048, 256, 0, stream>>>(x, xb, (M_TOT*DIM_)/4);
  tconv_kernel<<<dim3(N_QKV/64, DIM_/64), 256, 0, stream>>>(w_qkv, wqkvT, DIM_, N_QKV);
  tconv_kernel<<<dim3(DIM_/64, DIM_/64), 256, 0, stream>>>(w_out, woutT, DIM_, DIM_);

  // QKV: 256x192 tiles -> grid 16x32 = 512 blocks = 2 full CU rounds
  gemm3<256,192,0><<<dim3(N_QKV/192, M_TOT/256), 512, 0, stream>>>(
      xb, wqkvT, M_TOT, N_QKV, DIM_, Qb, Kb, Vtb, nullptr, nullptr);

  attn_kernel<<<B_SZ*NH*(SEQ/64), 256, 0, stream>>>(Qb, Kb, Vtb, Aob);

  // OUT: 128x256 tiles -> grid 4x64 = 256 blocks = 1 full CU round
  gemm3<128,256,1><<<dim3(DIM_/256, M_TOT/128), 512, 0, stream>>>(
      Aob, woutT, M_TOT, DIM_, DIM_, nullptr, nullptr, nullptr, b_out, out);
}